// Round 6
// baseline (267.040 us; speedup 1.0000x reference)
//
#include <hip/hip_runtime.h>
#include <math.h>

// ---------------------------------------------------------------------------
// KAN-Conv CIFAR net on gfx950, round 6.
// vs round 5: (1) row-streaming conv inner loop -- each of the 16 distinct
// act positions per (channel, pooled pixel) is read from LDS exactly once
// (32 b128/ch vs 72); (2) og forced wave-uniform via readfirstlane (all
// layers use PPB*FS==64) so weight loads scalarize to s_load (SMEM pipe,
// zero VALU/LDS cost); (3) smaller act tiles: L1 32.6KB/1024 blocks,
// L2 27.6KB/1024 blocks -> 4 blocks/CU. No weight staging in LDS.
// ---------------------------------------------------------------------------

#define BATCH 256

__device__ __forceinline__ void bspline_basis(float x, float bs[6]) {
    const float h = 2.0f / 3.0f;
    float g[10];
#pragma unroll
    for (int i = 0; i < 10; ++i) g[i] = (float)(i - 3) * h - 1.0f;
    float b[9];
#pragma unroll
    for (int i = 0; i < 9; ++i) b[i] = (x >= g[i] && x < g[i + 1]) ? 1.0f : 0.0f;
#pragma unroll
    for (int j = 1; j <= 3; ++j) {
        const float inv_d = 1.0f / ((float)j * h);
#pragma unroll
        for (int i = 0; i + j < 9; ++i) {
            float left  = (x - g[i]) * inv_d;
            float right = (g[i + j + 1] - x) * inv_d;
            b[i] = left * b[i] + right * b[i + 1];
        }
    }
#pragma unroll
    for (int i = 0; i < 6; ++i) bs[i] = b[i];
}

// Fuse {base_w, spline_w*scaler} into 8-float records for all three layers.
__global__ __launch_bounds__(256) void prep_weights(
        const float* __restrict__ bw1, const float* __restrict__ sw1, const float* __restrict__ sc1,
        const float* __restrict__ bw2, const float* __restrict__ sw2, const float* __restrict__ sc2,
        const float* __restrict__ bw3, const float* __restrict__ sw3, const float* __restrict__ sc3,
        float* __restrict__ w1, float* __restrict__ w2, float* __restrict__ w3) {
    int i = blockIdx.x * blockDim.x + threadIdx.x;
    const float *bw, *sw, *sc;
    float* dst;
    int j;
    if (i < 216)       { bw = bw1; sw = sw1; sc = sc1; dst = w1; j = i; }
    else if (i < 1368) { bw = bw2; sw = sw2; sc = sc2; dst = w2; j = i - 216; }
    else if (i < 5976) { bw = bw3; sw = sw3; sc = sc3; dst = w3; j = i - 1368; }
    else return;
    float s = sc[j];
    float4* o = (float4*)(dst + (size_t)j * 8);
    o[0] = make_float4(bw[j], sw[j * 6 + 0] * s, sw[j * 6 + 1] * s, sw[j * 6 + 2] * s);
    o[1] = make_float4(sw[j * 6 + 3] * s, sw[j * 6 + 4] * s, sw[j * 6 + 5] * s, 0.0f);
}

// Fused: basis precompute (LDS) + KAN conv3x3(pad1) + maxpool2.
// x: [B,C,H,W]; wrec: [O, C*9, 8] fused; out: [B,O,H/2,W/2].
// VS: vertical split across blocks. FS: channel split within block.
template <int C, int O, int GO, int H, int W, int VS, int FS, int NT>
__global__ __launch_bounds__(NT, 2) void kan_conv_pool(
        const float* __restrict__ x,
        const float* __restrict__ wrec,
        float* __restrict__ out) {
    constexpr int PH = H / 2, PW = W / 2;
    constexpr int PR = PH / VS;            // pooled rows per block
    constexpr int R  = 2 * PR + 2;         // input tile rows (incl. halo)
    constexpr int TC = W + 2;              // input tile cols (incl. halo)
    constexpr int CP = TC / 2;             // cols per parity plane
    constexpr int F  = C * 9;
    constexpr int PPB = PR * PW;           // pooled pixels per block
    constexpr int NOG = O / GO;
    constexpr int CS = C / FS;             // channels per f-slice
    constexpr int PLANE = C * R * 2 * CP;  // float4 per (lo|hi) region
    static_assert(NT == NOG * FS * PPB, "thread mapping");
    static_assert((PPB * FS) % 64 == 0, "og must be wave-uniform");
    static_assert(FS == 1 || NT * GO <= 2 * PLANE, "reduce buffer fits");

    __shared__ float4 s_act[2 * PLANE];    // [0]=lo plane, [PLANE]=hi plane

    const int tid = threadIdx.x;
    const int bid = blockIdx.x;
    const int b = (VS > 1) ? (bid / VS) : bid;
    const int v = (VS > 1) ? (bid % VS) : 0;
    const int r0 = v * (2 * PR) - 1;       // global row of tile row 0

    // ---- Stage: zero-padded x -> [silu | b0..b5] records in LDS
    const float* xb = x + (size_t)b * C * H * W;
    for (int i = tid; i < C * R * TC; i += NT) {
        int cc  = i / (R * TC);
        int rr  = (i / TC) % R;
        int col = i % TC;
        int gr = r0 + rr, gc = col - 1;
        float val = 0.0f;
        if ((unsigned)gr < (unsigned)H && (unsigned)gc < (unsigned)W)
            val = xb[(cc * H + gr) * W + gc];
        float silu = val / (1.0f + __expf(-val));
        float bs[6];
        bspline_basis(val, bs);
        int idx = ((cc * R + rr) * 2 + (col & 1)) * CP + (col >> 1);
        s_act[idx]         = make_float4(silu, bs[0], bs[1], bs[2]);
        s_act[PLANE + idx] = make_float4(bs[3], bs[4], bs[5], 0.0f);
    }
    __syncthreads();

    // ---- Thread mapping (og wave-uniform by construction)
    const int px = tid % PPB;
    const int fh = (tid / PPB) % FS;
    int og = tid / (PPB * FS);
    og = __builtin_amdgcn_readfirstlane(og);   // force SGPR -> s_load weights
    const int phl = px / PW, pw = px % PW;
    const int o0 = og * GO;

    float acc[GO][4];
#pragma unroll
    for (int g = 0; g < GO; ++g)
#pragma unroll
        for (int p = 0; p < 4; ++p) acc[g][p] = 0.f;

    const float* wbase = wrec + (size_t)o0 * F * 8;

#pragma unroll 1
    for (int cc = 0; cc < CS; ++cc) {
        const int c = fh * CS + cc;
        const float4* plo = s_act + c * (R * 2 * CP);
        const float4* phi = plo + PLANE;
#pragma unroll
        for (int iy = 0; iy < 4; ++iy) {
            const int rr = 2 * phl + iy;
            float4 alo[4], ahi[4];
#pragma unroll
            for (int s = 0; s < 4; ++s) {
                const int off = (rr * 2 + (s & 1)) * CP + pw + (s >> 1);
                alo[s] = plo[off];
                ahi[s] = phi[off];
            }
#pragma unroll
            for (int ky = 0; ky < 3; ++ky) {
                const int dy = iy - ky;
                if (dy < 0 || dy > 1) continue;   // compile-time prune
#pragma unroll
                for (int kx = 0; kx < 3; ++kx) {
                    const int f = c * 9 + ky * 3 + kx;
#pragma unroll
                    for (int g = 0; g < GO; ++g) {
                        const float* wr = wbase + ((size_t)g * F + f) * 8;
                        float4 wl = *(const float4*)wr;
                        float wx = wr[4], wy = wr[5], wz = wr[6];
#pragma unroll
                        for (int dx = 0; dx < 2; ++dx) {
                            const int s = kx + dx;
                            acc[g][dy * 2 + dx] +=
                                alo[s].x * wl.x + alo[s].y * wl.y +
                                alo[s].z * wl.z + alo[s].w * wl.w +
                                ahi[s].x * wx + ahi[s].y * wy + ahi[s].z * wz;
                        }
                    }
                }
            }
        }
    }

    // ---- f-split reduction (reduce buffer aliases the act planes)
    if (FS > 1) {
        float4* s_red = s_act;
        __syncthreads();                   // act reads done before overwrite
#pragma unroll
        for (int g = 0; g < GO; ++g)
            s_red[tid * GO + g] = make_float4(acc[g][0], acc[g][1], acc[g][2], acc[g][3]);
        __syncthreads();
        if (fh != 0) return;
#pragma unroll
        for (int fq = 1; fq < FS; ++fq)
#pragma unroll
            for (int g = 0; g < GO; ++g) {
                float4 t = s_red[(tid + fq * PPB) * GO + g];
                acc[g][0] += t.x; acc[g][1] += t.y; acc[g][2] += t.z; acc[g][3] += t.w;
            }
    }

    // ---- maxpool + store
    const int phg = v * PR + phl;
#pragma unroll
    for (int g = 0; g < GO; ++g) {
        float m = fmaxf(fmaxf(acc[g][0], acc[g][1]), fmaxf(acc[g][2], acc[g][3]));
        out[(((size_t)b * O + o0 + g) * PH + phg) * PW + pw] = m;
    }
}

// out[n,o] = dot(h[n,:512], w[o,:512]) + bias[o]
__global__ __launch_bounds__(256) void linear_kernel(const float* __restrict__ h,
                                                     const float* __restrict__ w,
                                                     const float* __restrict__ bias,
                                                     float* __restrict__ out) {
    int idx = blockIdx.x * blockDim.x + threadIdx.x;
    if (idx >= BATCH * 100) return;
    int o = idx % 100;
    int n = idx / 100;
    const float4* hp = (const float4*)(h + (size_t)n * 512);
    const float4* wp = (const float4*)(w + (size_t)o * 512);
    float acc = 0.f;
#pragma unroll 4
    for (int i = 0; i < 128; ++i) {
        float4 a = hp[i];
        float4 b = wp[i];
        acc += a.x * b.x + a.y * b.y + a.z * b.z + a.w * b.w;
    }
    out[idx] = acc + bias[o];
}

extern "C" void kernel_launch(void* const* d_in, const int* in_sizes, int n_in,
                              void* d_out, int out_size, void* d_ws, size_t ws_size,
                              hipStream_t stream) {
    const float* x     = (const float*)d_in[0];
    const float* c1_bw = (const float*)d_in[1];
    const float* c1_sw = (const float*)d_in[2];
    const float* c1_sc = (const float*)d_in[3];
    const float* c2_bw = (const float*)d_in[4];
    const float* c2_sw = (const float*)d_in[5];
    const float* c2_sc = (const float*)d_in[6];
    const float* c3_bw = (const float*)d_in[7];
    const float* c3_sw = (const float*)d_in[8];
    const float* c3_sc = (const float*)d_in[9];
    const float* lin_w = (const float*)d_in[10];
    const float* lin_b = (const float*)d_in[11];
    float* out = (float*)d_out;

    float* ws = (float*)d_ws;
    float* h1 = ws;                 // 256*8*16*16  = 524288
    float* h2 = h1 + 524288;        // 256*16*8*8   = 262144
    float* h3 = h2 + 262144;        // 256*32*4*4   = 131072
    float* w1 = h3 + 131072;        // 216*8  = 1728
    float* w2 = w1 + 1728;          // 1152*8 = 9216
    float* w3 = w2 + 9216;          // 4608*8 = 36864
    // total 965312 floats = 3.9 MB

    // Fused weight records (independent; launch first).
    prep_weights<<<24, 256, 0, stream>>>(
        c1_bw, c1_sw, c1_sc, c2_bw, c2_sw, c2_sc, c3_bw, c3_sw, c3_sc, w1, w2, w3);

    // L1: [256,3,32,32] -> [256,8,16,16]; VS=4, GO=4, FS=1, NT=128.
    //     PPB=64 -> og wave-uniform; LDS 32.6KB; 1024 blocks (4/CU).
    kan_conv_pool<3, 8, 4, 32, 32, 4, 1, 128><<<1024, 128, 0, stream>>>(x, w1, h1);
    // L2: [256,8,16,16] -> [256,16,8,8]; VS=4, GO=4, FS=4, NT=256.
    //     PPB*FS=64; LDS 27.6KB; 1024 blocks (4/CU).
    kan_conv_pool<8, 16, 4, 16, 16, 4, 4, 256><<<1024, 256, 0, stream>>>(h1, w2, h2);
    // L3: [256,16,8,8] -> [256,32,4,4]; VS=1, GO=4, FS=4, NT=512.
    //     PPB*FS=64; LDS 51.2KB; 256 blocks.
    kan_conv_pool<16, 32, 4, 8, 8, 1, 4, 512><<<256, 512, 0, stream>>>(h2, w3, h3);
    // Linear: [256,512] @ [100,512]^T + b.
    linear_kernel<<<100, 256, 0, stream>>>(h3, lin_w, lin_b, out);
}

// Round 7
// 173.294 us; speedup vs baseline: 1.5410x; 1.5410x over previous
//
#include <hip/hip_runtime.h>
#include <math.h>

// ---------------------------------------------------------------------------
// KAN-Conv CIFAR net on gfx950, round 7.
// vs round 6: inner loop restructured for BOUNDED register pressure:
// unroll-1 on cc AND ky; per (cc,ky) body = 8 act positions (16 ds_read_b128,
// 64 VGPRs) + <=3*GO*7 weight floats in flight + GO*4 acc. No readfirstlane
// (was a correctness trap). Occupancy raised: all conv tiles <= 33 KB LDS,
// grids 512-1024 blocks -> >=2 blocks/CU, 8-16 waves/CU.
// ---------------------------------------------------------------------------

#define BATCH 256

__device__ __forceinline__ void bspline_basis(float x, float bs[6]) {
    const float h = 2.0f / 3.0f;
    float g[10];
#pragma unroll
    for (int i = 0; i < 10; ++i) g[i] = (float)(i - 3) * h - 1.0f;
    float b[9];
#pragma unroll
    for (int i = 0; i < 9; ++i) b[i] = (x >= g[i] && x < g[i + 1]) ? 1.0f : 0.0f;
#pragma unroll
    for (int j = 1; j <= 3; ++j) {
        const float inv_d = 1.0f / ((float)j * h);
#pragma unroll
        for (int i = 0; i + j < 9; ++i) {
            float left  = (x - g[i]) * inv_d;
            float right = (g[i + j + 1] - x) * inv_d;
            b[i] = left * b[i] + right * b[i + 1];
        }
    }
#pragma unroll
    for (int i = 0; i < 6; ++i) bs[i] = b[i];
}

// Fuse {base_w, spline_w*scaler} into 8-float records for all three layers.
__global__ __launch_bounds__(256) void prep_weights(
        const float* __restrict__ bw1, const float* __restrict__ sw1, const float* __restrict__ sc1,
        const float* __restrict__ bw2, const float* __restrict__ sw2, const float* __restrict__ sc2,
        const float* __restrict__ bw3, const float* __restrict__ sw3, const float* __restrict__ sc3,
        float* __restrict__ w1, float* __restrict__ w2, float* __restrict__ w3) {
    int i = blockIdx.x * blockDim.x + threadIdx.x;
    const float *bw, *sw, *sc;
    float* dst;
    int j;
    if (i < 216)       { bw = bw1; sw = sw1; sc = sc1; dst = w1; j = i; }
    else if (i < 1368) { bw = bw2; sw = sw2; sc = sc2; dst = w2; j = i - 216; }
    else if (i < 5976) { bw = bw3; sw = sw3; sc = sc3; dst = w3; j = i - 1368; }
    else return;
    float s = sc[j];
    float4* o = (float4*)(dst + (size_t)j * 8);
    o[0] = make_float4(bw[j], sw[j * 6 + 0] * s, sw[j * 6 + 1] * s, sw[j * 6 + 2] * s);
    o[1] = make_float4(sw[j * 6 + 3] * s, sw[j * 6 + 4] * s, sw[j * 6 + 5] * s, 0.0f);
}

// Fused: basis precompute (LDS) + KAN conv3x3(pad1) + maxpool2.
// x: [B,C,H,W]; wrec: [O, C*9, 8] fused; out: [B,O,H/2,W/2].
// VS: vertical split across blocks. FS: channel split within block (must
// divide C), LDS-reduced.
template <int C, int O, int GO, int H, int W, int VS, int FS, int NT>
__global__ __launch_bounds__(NT, 2) void kan_conv_pool(
        const float* __restrict__ x,
        const float* __restrict__ wrec,
        float* __restrict__ out) {
    constexpr int PH = H / 2, PW = W / 2;
    constexpr int PR = PH / VS;            // pooled rows per block
    constexpr int R  = 2 * PR + 2;         // input tile rows (incl. halo)
    constexpr int TC = W + 2;              // input tile cols (incl. halo)
    constexpr int CP = TC / 2;             // cols per parity plane
    constexpr int F  = C * 9;
    constexpr int PPB = PR * PW;           // pooled pixels per block
    constexpr int NOG = O / GO;
    constexpr int CS = C / FS;             // channels per f-slice
    constexpr int PLANE = C * R * 2 * CP;  // float4 per (lo|hi) region
    static_assert(NT == NOG * FS * PPB, "thread mapping");
    static_assert(FS == 1 || NT * GO <= 2 * PLANE, "reduce buffer fits");

    __shared__ float4 s_act[2 * PLANE];    // [0]=lo plane, [PLANE]=hi plane

    const int tid = threadIdx.x;
    const int bid = blockIdx.x;
    const int b = (VS > 1) ? (bid / VS) : bid;
    const int v = (VS > 1) ? (bid % VS) : 0;
    const int r0 = v * (2 * PR) - 1;       // global row of tile row 0

    // ---- Stage: zero-padded x -> [silu | b0..b5] records in LDS
    const float* xb = x + (size_t)b * C * H * W;
    for (int i = tid; i < C * R * TC; i += NT) {
        int cc  = i / (R * TC);
        int rr  = (i / TC) % R;
        int col = i % TC;
        int gr = r0 + rr, gc = col - 1;
        float val = 0.0f;
        if ((unsigned)gr < (unsigned)H && (unsigned)gc < (unsigned)W)
            val = xb[(cc * H + gr) * W + gc];
        float silu = val / (1.0f + __expf(-val));
        float bs[6];
        bspline_basis(val, bs);
        int idx = ((cc * R + rr) * 2 + (col & 1)) * CP + (col >> 1);
        s_act[idx]         = make_float4(silu, bs[0], bs[1], bs[2]);
        s_act[PLANE + idx] = make_float4(bs[3], bs[4], bs[5], 0.0f);
    }
    __syncthreads();

    // ---- Thread mapping: tid = og*(FS*PPB) + fh*PPB + px
    const int px = tid % PPB;
    const int fh = (tid / PPB) % FS;
    const int og = tid / (PPB * FS);
    const int phl = px / PW, pw = px % PW;
    const int o0 = og * GO;

    float acc[GO][4];
#pragma unroll
    for (int g = 0; g < GO; ++g)
#pragma unroll
        for (int p = 0; p < 4; ++p) acc[g][p] = 0.f;

    const float* wbase = wrec + (size_t)o0 * F * 8;

#pragma unroll 1
    for (int cc = 0; cc < CS; ++cc) {
        const int c = fh * CS + cc;
        const float4* plo = s_act + c * (R * 2 * CP);
        const float4* phi = plo + PLANE;
#pragma unroll 1
        for (int ky = 0; ky < 3; ++ky) {
            // Act positions for this ky: rows 2*phl+ky+{0,1}, cols 2*pw+{0..3}.
            float4 alo[2][4], ahi[2][4];
#pragma unroll
            for (int dy = 0; dy < 2; ++dy) {
                const int rr = 2 * phl + ky + dy;
#pragma unroll
                for (int s = 0; s < 4; ++s) {
                    const int off = (rr * 2 + (s & 1)) * CP + pw + (s >> 1);
                    alo[dy][s] = plo[off];
                    ahi[dy][s] = phi[off];
                }
            }
#pragma unroll
            for (int kx = 0; kx < 3; ++kx) {
#pragma unroll
                for (int g = 0; g < GO; ++g) {
                    const float* wr = wbase + ((size_t)g * F + (c * 9 + ky * 3 + kx)) * 8;
                    float4 wl = *(const float4*)wr;
                    float wx = wr[4], wy = wr[5], wz = wr[6];
#pragma unroll
                    for (int dy = 0; dy < 2; ++dy) {
#pragma unroll
                        for (int dx = 0; dx < 2; ++dx) {
                            const int s = kx + dx;
                            acc[g][dy * 2 + dx] +=
                                alo[dy][s].x * wl.x + alo[dy][s].y * wl.y +
                                alo[dy][s].z * wl.z + alo[dy][s].w * wl.w +
                                ahi[dy][s].x * wx + ahi[dy][s].y * wy +
                                ahi[dy][s].z * wz;
                        }
                    }
                }
            }
        }
    }

    // ---- f-split reduction (reduce buffer aliases the act planes)
    if (FS > 1) {
        float4* s_red = s_act;
        __syncthreads();                   // act reads done before overwrite
#pragma unroll
        for (int g = 0; g < GO; ++g)
            s_red[tid * GO + g] = make_float4(acc[g][0], acc[g][1], acc[g][2], acc[g][3]);
        __syncthreads();
        if (fh != 0) return;
#pragma unroll
        for (int fq = 1; fq < FS; ++fq)
#pragma unroll
            for (int g = 0; g < GO; ++g) {
                float4 t = s_red[(tid + fq * PPB) * GO + g];
                acc[g][0] += t.x; acc[g][1] += t.y; acc[g][2] += t.z; acc[g][3] += t.w;
            }
    }

    // ---- maxpool + store
    const int phg = v * PR + phl;
#pragma unroll
    for (int g = 0; g < GO; ++g) {
        float m = fmaxf(fmaxf(acc[g][0], acc[g][1]), fmaxf(acc[g][2], acc[g][3]));
        out[(((size_t)b * O + o0 + g) * PH + phg) * PW + pw] = m;
    }
}

// out[n,o] = dot(h[n,:512], w[o,:512]) + bias[o]
__global__ __launch_bounds__(256) void linear_kernel(const float* __restrict__ h,
                                                     const float* __restrict__ w,
                                                     const float* __restrict__ bias,
                                                     float* __restrict__ out) {
    int idx = blockIdx.x * blockDim.x + threadIdx.x;
    if (idx >= BATCH * 100) return;
    int o = idx % 100;
    int n = idx / 100;
    const float4* hp = (const float4*)(h + (size_t)n * 512);
    const float4* wp = (const float4*)(w + (size_t)o * 512);
    float acc = 0.f;
#pragma unroll 4
    for (int i = 0; i < 128; ++i) {
        float4 a = hp[i];
        float4 b = wp[i];
        acc += a.x * b.x + a.y * b.y + a.z * b.z + a.w * b.w;
    }
    out[idx] = acc + bias[o];
}

extern "C" void kernel_launch(void* const* d_in, const int* in_sizes, int n_in,
                              void* d_out, int out_size, void* d_ws, size_t ws_size,
                              hipStream_t stream) {
    const float* x     = (const float*)d_in[0];
    const float* c1_bw = (const float*)d_in[1];
    const float* c1_sw = (const float*)d_in[2];
    const float* c1_sc = (const float*)d_in[3];
    const float* c2_bw = (const float*)d_in[4];
    const float* c2_sw = (const float*)d_in[5];
    const float* c2_sc = (const float*)d_in[6];
    const float* c3_bw = (const float*)d_in[7];
    const float* c3_sw = (const float*)d_in[8];
    const float* c3_sc = (const float*)d_in[9];
    const float* lin_w = (const float*)d_in[10];
    const float* lin_b = (const float*)d_in[11];
    float* out = (float*)d_out;

    float* ws = (float*)d_ws;
    float* h1 = ws;                 // 256*8*16*16  = 524288
    float* h2 = h1 + 524288;        // 256*16*8*8   = 262144
    float* h3 = h2 + 262144;        // 256*32*4*4   = 131072
    float* w1 = h3 + 131072;        // 216*8  = 1728
    float* w2 = w1 + 1728;          // 1152*8 = 9216
    float* w3 = w2 + 9216;          // 4608*8 = 36864
    // total 965312 floats = 3.9 MB

    // Fused weight records (independent; launch first).
    prep_weights<<<24, 256, 0, stream>>>(
        c1_bw, c1_sw, c1_sc, c2_bw, c2_sw, c2_sc, c3_bw, c3_sw, c3_sc, w1, w2, w3);

    // L1: [256,3,32,32] -> [256,8,16,16]; VS=4, GO=4, FS=1, NT=128.
    //     LDS 32.6KB; 1024 blocks (4/CU, 8 waves/CU).
    kan_conv_pool<3, 8, 4, 32, 32, 4, 1, 128><<<1024, 128, 0, stream>>>(x, w1, h1);
    // L2: [256,8,16,16] -> [256,16,8,8]; VS=4, GO=4, FS=4, NT=256.
    //     LDS 27.6KB; 1024 blocks (4/CU, 16 waves/CU).
    kan_conv_pool<8, 16, 4, 16, 16, 4, 4, 256><<<1024, 256, 0, stream>>>(h1, w2, h2);
    // L3: [256,16,8,8] -> [256,32,4,4]; VS=2, GO=4, FS=4, NT=256.
    //     LDS 30.7KB; 512 blocks (2/CU, 8 waves/CU).
    kan_conv_pool<16, 32, 4, 8, 8, 2, 4, 256><<<512, 256, 0, stream>>>(h2, w3, h3);
    // Linear: [256,512] @ [100,512]^T + b.
    linear_kernel<<<100, 256, 0, stream>>>(h3, lin_w, lin_b, out);
}